// Round 2
// baseline (10839.342 us; speedup 1.0000x reference)
//
#include <hip/hip_runtime.h>

// ---- problem dims ----
#define NN 20000
#define NE 640000
#define FF 128
#define H1 64
#define H2 32
#define RR 65
#define BQ 4096
#define NR (NN*RR)

// ---- small scratch block offsets (ints within sm[1024]) ----
#define SM_HIST_A 0
#define SM_START_A 128
#define SM_CUR_A 256
#define SM_HIST_B 384
#define SM_START_B 512
#define SM_CUR_B 640
#define SM_HACC 768   // 32 floats
#define SM_V 832      // 32 floats

#define CPB1 16       // blocks per relation, layer 1 (grid 65*16=1040 ~ 4/CU)
#define CPB2 16       // layer 2

// ===================== histogram: cnt[(dst,rel)] + per-type counts =====================
__global__ __launch_bounds__(256) void k_hist(
    const int* __restrict__ ei, const int* __restrict__ etA, const int* __restrict__ etB,
    int* __restrict__ cntA, int* __restrict__ cntB, int* __restrict__ sm) {
  __shared__ int lh[2 * RR];
  int tid = threadIdx.x;
  for (int i = tid; i < 2 * RR; i += blockDim.x) lh[i] = 0;
  __syncthreads();
  int e = blockIdx.x * blockDim.x + tid;
  if (e < NE) {
    int dst = ei[NE + e];
    int ta = etA[e], tb = etB[e];
    atomicAdd(&cntA[dst * RR + ta], 1);
    atomicAdd(&cntB[dst * RR + tb], 1);
    atomicAdd(&lh[ta], 1);
    atomicAdd(&lh[RR + tb], 1);
  }
  __syncthreads();
  for (int i = tid; i < 2 * RR; i += blockDim.x) {
    int c = lh[i];
    if (c) atomicAdd(&sm[(i < RR) ? (SM_HIST_A + i) : (SM_HIST_B + (i - RR))], c);
  }
}

// ===================== exclusive prefix over 65 bins =====================
__global__ __launch_bounds__(128) void k_prefix(int* __restrict__ sm) {
  int w = threadIdx.x >> 6;
  if ((threadIdx.x & 63) == 0 && w < 2) {
    int hb = w ? SM_HIST_B : SM_HIST_A;
    int sb = w ? SM_START_B : SM_START_A;
    int cb = w ? SM_CUR_B : SM_CUR_A;
    int h[RR];
#pragma unroll
    for (int r = 0; r < RR; ++r) h[r] = sm[hb + r];
    int s = 0;
#pragma unroll
    for (int r = 0; r < RR; ++r) { sm[sb + r] = s; sm[cb + r] = s; s += h[r]; }
  }
}

// ===================== counting-sort scatter =====================
__global__ __launch_bounds__(256) void k_scatter(
    const int* __restrict__ etA, const int* __restrict__ etB,
    int* __restrict__ sm, int* __restrict__ ordA, int* __restrict__ ordB) {
  __shared__ int lhA[RR], lbA[RR], lhB[RR], lbB[RR];
  int tid = threadIdx.x;
  for (int i = tid; i < RR; i += blockDim.x) { lhA[i] = 0; lhB[i] = 0; }
  __syncthreads();
  int e = blockIdx.x * blockDim.x + tid;
  int ta = 0, tb = 0, ra = 0, rb = 0;
  bool valid = (e < NE);
  if (valid) {
    ta = etA[e]; tb = etB[e];
    ra = atomicAdd(&lhA[ta], 1);
    rb = atomicAdd(&lhB[tb], 1);
  }
  __syncthreads();
  for (int i = tid; i < RR; i += blockDim.x) {
    if (lhA[i]) lbA[i] = atomicAdd(&sm[SM_CUR_A + i], lhA[i]);
    if (lhB[i]) lbB[i] = atomicAdd(&sm[SM_CUR_B + i], lhB[i]);
  }
  __syncthreads();
  if (valid) { ordA[lbA[ta] + ra] = e; ordB[lbB[tb] + rb] = e; }
}

// ===================== counts -> 1/cnt (float, in place) =====================
__global__ __launch_bounds__(256) void k_inv(int* __restrict__ cntA, int* __restrict__ cntB) {
  int i = blockIdx.x * blockDim.x + threadIdx.x;
  if (i < NR) {
    int c = cntA[i]; ((float*)cntA)[i] = (c > 0) ? 1.0f / (float)c : 0.0f;
    c = cntB[i];     ((float*)cntB)[i] = (c > 0) ? 1.0f / (float)c : 0.0f;
  }
}

// ===================== layer-1 root term =====================
__global__ __launch_bounds__(256) void k_root1(
    const float* __restrict__ xo, const float* __restrict__ xa,
    const float* __restrict__ rt, const float* __restrict__ b,
    float* __restrict__ yo, float* __restrict__ yaa, float* __restrict__ ya) {
  int lane = threadIdx.x & 63;
  int n = (blockIdx.x * blockDim.x + threadIdx.x) >> 6;
  if (n >= NN) return;
  const float4* xo4 = (const float4*)(xo + (size_t)n * FF);
  const float4* xa4 = (const float4*)(xa + (size_t)n * FF);
  float so = b[lane], sa = so;
#pragma unroll
  for (int j = 0; j < FF / 4; ++j) {
    float vo[4], va[4];
    *(float4*)vo = xo4[j];
    *(float4*)va = xa4[j];
#pragma unroll
    for (int t = 0; t < 4; ++t) {
      float wv = rt[(4 * j + t) * H1 + lane];
      so = fmaf(vo[t], wv, so);
      sa = fmaf(va[t], wv, sa);
    }
  }
  yo[(size_t)n * H1 + lane] = so;
  yaa[(size_t)n * H1 + lane] = so;
  ya[(size_t)n * H1 + lane] = sa;
}

// ===================== layer-1 edge transform+scatter ===============================
// W_r staged in LDS [k][64] (lane-consecutive reads = conflict-free).
// EPG edges per wave iteration share each W read: per k, 1 ds_read -> NIN*EPG FMAs.
template <int NIN, int EPG>
__global__ __launch_bounds__(256, 4) void k_edge1(
    const int* __restrict__ ei, const int* __restrict__ ord,
    const int* __restrict__ sm, int startOff, int histOff,
    const float* __restrict__ invc, const float* __restrict__ W1,
    const float* __restrict__ x0, const float* __restrict__ x1in,
    float* __restrict__ y0, float* __restrict__ y1) {
  __shared__ float wlds[FF * H1];          // 32 KB
  const int r = blockIdx.x / CPB1;
  {
    const float4* Wr = (const float4*)(W1 + (size_t)r * (FF * H1));
    float4* wl = (float4*)wlds;
#pragma unroll
    for (int i = 0; i < (FF * H1 / 4) / 256; ++i)
      wl[threadIdx.x + i * 256] = Wr[threadIdx.x + i * 256];
  }
  __syncthreads();
  const int chunk = blockIdx.x - r * CPB1;
  const int lane = threadIdx.x & 63;
  const int wv = chunk * 4 + (threadIdx.x >> 6);
  const int stride = CPB1 * 4;
  const int s0 = sm[startOff + r];
  const int cnt = sm[histOff + r];
  const int ngroups = (cnt + EPG - 1) / EPG;
  const float* xin[2] = {x0, x1in};
  float* yout[2] = {y0, y1};

  for (int G = wv; G < ngroups; G += stride) {
    const int base = s0 + G * EPG;
    const int lim = cnt - G * EPG;       // >0 guaranteed
    int src[EPG], dst[EPG];
    float inv[EPG];
#pragma unroll
    for (int i = 0; i < EPG; ++i) {
      int pi = (i < lim) ? i : 0;
      int e = ord[base + pi];
      src[i] = ei[e];
      dst[i] = ei[NE + e];
      inv[i] = (i < lim) ? invc[dst[i] * RR + r] : 0.f;
    }
    float acc[NIN][EPG][4];
#pragma unroll
    for (int n = 0; n < NIN; ++n)
#pragma unroll
      for (int i = 0; i < EPG; ++i)
#pragma unroll
        for (int t = 0; t < 4; ++t) acc[n][i][t] = 0.f;

#pragma unroll
    for (int j = 0; j < FF / 4; ++j) {
      float xv[NIN][EPG][4];
#pragma unroll
      for (int n = 0; n < NIN; ++n)
#pragma unroll
        for (int i = 0; i < EPG; ++i)
          *(float4*)xv[n][i] = ((const float4*)(xin[n] + (size_t)src[i] * FF))[j];
#pragma unroll
      for (int t = 0; t < 4; ++t) {
        float wv_ = wlds[(4 * j + t) * H1 + lane];
#pragma unroll
        for (int n = 0; n < NIN; ++n)
#pragma unroll
          for (int i = 0; i < EPG; ++i)
            acc[n][i][t] = fmaf(xv[n][i][t], wv_, acc[n][i][t]);
      }
    }
#pragma unroll
    for (int n = 0; n < NIN; ++n)
#pragma unroll
      for (int i = 0; i < EPG; ++i) {
        float s = (acc[n][i][0] + acc[n][i][1]) + (acc[n][i][2] + acc[n][i][3]);
        unsafeAtomicAdd(&yout[n][(size_t)dst[i] * H1 + lane], s * inv[i]);
      }
  }
}

// ===================== relu over contiguous x1 buffers =====================
__global__ __launch_bounds__(256) void k_relu4(float4* __restrict__ a, int n4) {
  int i = blockIdx.x * blockDim.x + threadIdx.x;
  if (i < n4) {
    float4 v = a[i];
    v.x = fmaxf(v.x, 0.f); v.y = fmaxf(v.y, 0.f);
    v.z = fmaxf(v.z, 0.f); v.w = fmaxf(v.w, 0.f);
    a[i] = v;
  }
}

// ===================== layer-2 root term =====================
__global__ __launch_bounds__(256) void k_root2(
    const float* __restrict__ x1, const float* __restrict__ rt,
    const float* __restrict__ b, float* __restrict__ y) {
  int i = blockIdx.x * blockDim.x + threadIdx.x;
  if (i >= NN * H2) return;
  int o = i & (H2 - 1);
  int n = i >> 5;
  const float4* x4 = (const float4*)(x1 + (size_t)n * H1);
  float s = b[o];
#pragma unroll
  for (int j = 0; j < H1 / 4; ++j) {
    float v[4];
    *(float4*)v = x4[j];
#pragma unroll
    for (int t = 0; t < 4; ++t) s = fmaf(v[t], rt[(4 * j + t) * H2 + o], s);
  }
  y[i] = s;
}

// ===================== layer-2 edge transform+scatter ===============================
// lane = (half = lane>>5 selects k-range, o = lane&31); W2_r in LDS [k][32].
template <int NIN, int EPG>
__global__ __launch_bounds__(256, 4) void k_edge2(
    const int* __restrict__ ei, const int* __restrict__ ord,
    const int* __restrict__ sm, int startOff, int histOff,
    const float* __restrict__ invc, const float* __restrict__ W2,
    const float* __restrict__ x0, const float* __restrict__ x1in,
    float* __restrict__ y0, float* __restrict__ y1) {
  __shared__ float wlds[H1 * H2];          // 8 KB
  const int r = blockIdx.x / CPB2;
  {
    const float4* Wr = (const float4*)(W2 + (size_t)r * (H1 * H2));
    float4* wl = (float4*)wlds;
#pragma unroll
    for (int i = 0; i < (H1 * H2 / 4) / 256; ++i)
      wl[threadIdx.x + i * 256] = Wr[threadIdx.x + i * 256];
  }
  __syncthreads();
  const int chunk = blockIdx.x - r * CPB2;
  const int lane = threadIdx.x & 63;
  const int half = lane >> 5;
  const int o = lane & 31;
  const int wv = chunk * 4 + (threadIdx.x >> 6);
  const int stride = CPB2 * 4;
  const int s0 = sm[startOff + r];
  const int cnt = sm[histOff + r];
  const int ngroups = (cnt + EPG - 1) / EPG;
  const float* xin[2] = {x0, x1in};
  float* yout[2] = {y0, y1};

  for (int G = wv; G < ngroups; G += stride) {
    const int base = s0 + G * EPG;
    const int lim = cnt - G * EPG;
    int src[EPG], dst[EPG];
    float inv[EPG];
#pragma unroll
    for (int i = 0; i < EPG; ++i) {
      int pi = (i < lim) ? i : 0;
      int e = ord[base + pi];
      src[i] = ei[e];
      dst[i] = ei[NE + e];
      inv[i] = (i < lim) ? invc[dst[i] * RR + r] : 0.f;
    }
    float acc[NIN][EPG][4];
#pragma unroll
    for (int n = 0; n < NIN; ++n)
#pragma unroll
      for (int i = 0; i < EPG; ++i)
#pragma unroll
        for (int t = 0; t < 4; ++t) acc[n][i][t] = 0.f;

#pragma unroll
    for (int c = 0; c < (H1 / 2) / 4; ++c) {   // 8 float4 chunks of this half's k-range
      float xv[NIN][EPG][4];
#pragma unroll
      for (int n = 0; n < NIN; ++n)
#pragma unroll
        for (int i = 0; i < EPG; ++i)
          *(float4*)xv[n][i] = ((const float4*)(xin[n] + (size_t)src[i] * H1 + half * (H1 / 2)))[c];
#pragma unroll
      for (int t = 0; t < 4; ++t) {
        float wv_ = wlds[(half * (H1 / 2) + 4 * c + t) * H2 + o];
#pragma unroll
        for (int n = 0; n < NIN; ++n)
#pragma unroll
          for (int i = 0; i < EPG; ++i)
            acc[n][i][t] = fmaf(xv[n][i][t], wv_, acc[n][i][t]);
      }
    }
#pragma unroll
    for (int n = 0; n < NIN; ++n)
#pragma unroll
      for (int i = 0; i < EPG; ++i) {
        float s = (acc[n][i][0] + acc[n][i][1]) + (acc[n][i][2] + acc[n][i][3]);
        s += __shfl_xor(s, 32);
        if (half == 0)
          unsafeAtomicAdd(&yout[n][(size_t)dst[i] * H2 + o], s * inv[i]);
      }
  }
}

// ===================== column sum of x2_o -> hacc[32] =====================
__global__ __launch_bounds__(256) void k_colsum(const float* __restrict__ x2o,
                                                float* __restrict__ hacc) {
  int tid = threadIdx.x;
  int col = tid & 31;
  int rgrp = blockIdx.x * (blockDim.x >> 5) + (tid >> 5);
  int nth = gridDim.x * (blockDim.x >> 5);
  float s = 0.f;
  for (int n = rgrp; n < NN; n += nth) s += x2o[(size_t)n * H2 + col];
  unsafeAtomicAdd(&hacc[col], s);
}

// ===================== h_os = sigmoid(mean); v = disc_w @ h_os =====================
__global__ __launch_bounds__(64) void k_disc(const float* __restrict__ hacc,
                                             const float* __restrict__ dw,
                                             float* __restrict__ vout) {
  __shared__ float hos[H2];
  int t = threadIdx.x;
  if (t < H2) hos[t] = 1.0f / (1.0f + expf(-hacc[t] / (float)NN));
  __syncthreads();
  if (t < H2) {
    float s = 0.f;
#pragma unroll
    for (int k = 0; k < H2; ++k) s = fmaf(dw[t * H2 + k], hos[k], s);
    vout[t] = s;
  }
}

// ===================== ret_os / ret_os_a (col0 shared) =====================
__global__ __launch_bounds__(256) void k_ret(
    const float* __restrict__ x2o, const float* __restrict__ x2oa, const float* __restrict__ x2oaa,
    const float* __restrict__ v, const float* __restrict__ db,
    float* __restrict__ ros, float* __restrict__ rosa) {
  int n = blockIdx.x * blockDim.x + threadIdx.x;
  if (n >= NN) return;
  const float4* a4 = (const float4*)(x2o + (size_t)n * H2);
  const float4* b4 = (const float4*)(x2oa + (size_t)n * H2);
  const float4* c4 = (const float4*)(x2oaa + (size_t)n * H2);
  const float4* v4 = (const float4*)v;
  float r0 = 0.f, r1 = 0.f, r2 = 0.f;
#pragma unroll
  for (int j = 0; j < H2 / 4; ++j) {
    float va[4], vb[4], vc[4], vv[4];
    *(float4*)va = a4[j]; *(float4*)vb = b4[j]; *(float4*)vc = c4[j]; *(float4*)vv = v4[j];
#pragma unroll
    for (int t = 0; t < 4; ++t) {
      r0 = fmaf(va[t], vv[t], r0);
      r1 = fmaf(vb[t], vv[t], r1);
      r2 = fmaf(vc[t], vv[t], r2);
    }
  }
  float bb = db[0];
  ros[n * 2] = r0 + bb;  ros[n * 2 + 1] = r1 + bb;
  rosa[n * 2] = r0 + bb; rosa[n * 2 + 1] = r2 + bb;
}

// ===================== classifier: log[b][r] =====================
__global__ __launch_bounds__(128) void k_cls(
    const int* __restrict__ idx, const float* __restrict__ x1o, const float* __restrict__ x2o,
    const float* __restrict__ attt, const float* __restrict__ cw, const float* __restrict__ cb,
    float* __restrict__ lg) {
  int b = blockIdx.x;
  int r = threadIdx.x;
  if (r >= RR) return;
  int i1 = idx[b], i2 = idx[BQ + b];
  float a0 = attt[0], a1 = attt[1];
  float acc = cb[r];
  const float4* q1 = (const float4*)(x1o + (size_t)i1 * H1);
  const float4* q2 = (const float4*)(x2o + (size_t)i1 * H2);
  const float4* q3 = (const float4*)(x1o + (size_t)i2 * H1);
  const float4* q4 = (const float4*)(x2o + (size_t)i2 * H2);
#pragma unroll
  for (int j = 0; j < H1 / 4; ++j) {
    float v[4]; *(float4*)v = q1[j];
#pragma unroll
    for (int t = 0; t < 4; ++t) acc = fmaf(a0 * v[t], cw[(4 * j + t) * RR + r], acc);
  }
#pragma unroll
  for (int j = 0; j < H2 / 4; ++j) {
    float v[4]; *(float4*)v = q2[j];
#pragma unroll
    for (int t = 0; t < 4; ++t) acc = fmaf(a1 * v[t], cw[(H1 + 4 * j + t) * RR + r], acc);
  }
#pragma unroll
  for (int j = 0; j < H1 / 4; ++j) {
    float v[4]; *(float4*)v = q3[j];
#pragma unroll
    for (int t = 0; t < 4; ++t) acc = fmaf(a0 * v[t], cw[(96 + 4 * j + t) * RR + r], acc);
  }
#pragma unroll
  for (int j = 0; j < H2 / 4; ++j) {
    float v[4]; *(float4*)v = q4[j];
#pragma unroll
    for (int t = 0; t < 4; ++t) acc = fmaf(a1 * v[t], cw[(96 + H1 + 4 * j + t) * RR + r], acc);
  }
  lg[(size_t)b * RR + r] = acc;
}

// ===================== launch =====================
extern "C" void kernel_launch(void* const* d_in, const int* in_sizes, int n_in,
                              void* d_out, int out_size, void* d_ws, size_t ws_size,
                              hipStream_t stream) {
  const float* x_o  = (const float*)d_in[0];
  const float* x_a  = (const float*)d_in[1];
  const int*   ei   = (const int*)d_in[2];
  const int*   etA  = (const int*)d_in[3];
  const int*   etB  = (const int*)d_in[4];
  const int*   idx  = (const int*)d_in[5];
  const float* W1   = (const float*)d_in[6];
  const float* rt1  = (const float*)d_in[7];
  const float* b1   = (const float*)d_in[8];
  const float* W2   = (const float*)d_in[9];
  const float* rt2  = (const float*)d_in[10];
  const float* b2   = (const float*)d_in[11];
  const float* attt = (const float*)d_in[12];
  const float* dw   = (const float*)d_in[13];
  const float* db   = (const float*)d_in[14];
  const float* cw   = (const float*)d_in[15];
  const float* cb   = (const float*)d_in[16];

  const size_t NRp = 1300224;
  int* wsI  = (int*)d_ws;
  int* cntA = wsI;
  int* cntB = wsI + NRp;
  int* sm   = wsI + 2 * NRp;
  int* ordA = sm + 1024;
  int* ordB = ordA + NE;
  float* x1o   = (float*)(ordB + NE);
  float* x1a   = x1o + (size_t)NN * H1;
  float* x1aa  = x1a + (size_t)NN * H1;
  float* x2oa  = x1aa + (size_t)NN * H1;
  float* x2oaa = x2oa + (size_t)NN * H2;
  float* smF   = (float*)sm;
  float* hacc  = smF + SM_HACC;
  float* vbuf  = smF + SM_V;

  float* outF   = (float*)d_out;
  float* o_log  = outF;
  float* o_ros  = outF + (size_t)BQ * RR;
  float* o_rosa = o_ros + (size_t)NN * 2;
  float* o_x2o  = o_rosa + (size_t)NN * 2;

  hipMemsetAsync(wsI, 0, (2 * NRp + 1024) * sizeof(int), stream);

  k_hist<<<(NE + 255) / 256, 256, 0, stream>>>(ei, etA, etB, cntA, cntB, sm);
  k_prefix<<<1, 128, 0, stream>>>(sm);
  k_scatter<<<(NE + 255) / 256, 256, 0, stream>>>(etA, etB, sm, ordA, ordB);
  k_inv<<<(NR + 255) / 256, 256, 0, stream>>>(cntA, cntB);

  k_root1<<<(NN * H1) / 256, 256, 0, stream>>>(x_o, x_a, rt1, b1, x1o, x1aa, x1a);
  k_edge1<2, 4><<<RR * CPB1, 256, 0, stream>>>(ei, ordA, sm, SM_START_A, SM_HIST_A,
                                               (const float*)cntA, W1, x_o, x_a, x1o, x1a);
  k_edge1<1, 8><<<RR * CPB1, 256, 0, stream>>>(ei, ordB, sm, SM_START_B, SM_HIST_B,
                                               (const float*)cntB, W1, x_o, nullptr, x1aa, nullptr);
  k_relu4<<<(3 * NN * H1 / 4 + 255) / 256, 256, 0, stream>>>((float4*)x1o, 3 * NN * H1 / 4);

  k_root2<<<(NN * H2 + 255) / 256, 256, 0, stream>>>(x1o, rt2, b2, o_x2o);
  k_root2<<<(NN * H2 + 255) / 256, 256, 0, stream>>>(x1a, rt2, b2, x2oa);
  k_root2<<<(NN * H2 + 255) / 256, 256, 0, stream>>>(x1aa, rt2, b2, x2oaa);
  k_edge2<2, 4><<<RR * CPB2, 256, 0, stream>>>(ei, ordA, sm, SM_START_A, SM_HIST_A,
                                               (const float*)cntA, W2, x1o, x1a, o_x2o, x2oa);
  k_edge2<1, 8><<<RR * CPB2, 256, 0, stream>>>(ei, ordB, sm, SM_START_B, SM_HIST_B,
                                               (const float*)cntB, W2, x1aa, nullptr, x2oaa, nullptr);

  k_colsum<<<128, 256, 0, stream>>>(o_x2o, hacc);
  k_disc<<<1, 64, 0, stream>>>(hacc, dw, vbuf);
  k_ret<<<(NN + 255) / 256, 256, 0, stream>>>(o_x2o, x2oa, x2oaa, vbuf, db, o_ros, o_rosa);
  k_cls<<<BQ, 128, 0, stream>>>(idx, x1o, o_x2o, attt, cw, cb, o_log);
}

// Round 3
// 3230.180 us; speedup vs baseline: 3.3556x; 3.3556x over previous
//
#include <hip/hip_runtime.h>

// ---- problem dims ----
#define NN 20000
#define NE 640000
#define FF 128
#define H1 64
#define H2 32
#define RR 65
#define BQ 4096
#define NR (NN*RR)

// ---- small scratch block offsets (ints within sm[1024]) ----
#define SM_HIST_A 0
#define SM_START_A 128
#define SM_CUR_A 256
#define SM_HIST_B 384
#define SM_START_B 512
#define SM_CUR_B 640
#define SM_HACC 768   // 32 floats
#define SM_V 832      // 32 floats

#define CPB1 20       // blocks per relation, layer 1 (65*20=1300 ~ 5/CU, LDS-capped)
#define CPB2 32       // layer 2 (65*32=2080 ~ 8/CU)

// ===================== histogram: cnt[(dst,rel)] + per-type counts =====================
__global__ __launch_bounds__(256) void k_hist(
    const int* __restrict__ ei, const int* __restrict__ etA, const int* __restrict__ etB,
    int* __restrict__ cntA, int* __restrict__ cntB, int* __restrict__ sm) {
  __shared__ int lh[2 * RR];
  int tid = threadIdx.x;
  for (int i = tid; i < 2 * RR; i += blockDim.x) lh[i] = 0;
  __syncthreads();
  int e = blockIdx.x * blockDim.x + tid;
  if (e < NE) {
    int dst = ei[NE + e];
    int ta = etA[e], tb = etB[e];
    atomicAdd(&cntA[dst * RR + ta], 1);
    atomicAdd(&cntB[dst * RR + tb], 1);
    atomicAdd(&lh[ta], 1);
    atomicAdd(&lh[RR + tb], 1);
  }
  __syncthreads();
  for (int i = tid; i < 2 * RR; i += blockDim.x) {
    int c = lh[i];
    if (c) atomicAdd(&sm[(i < RR) ? (SM_HIST_A + i) : (SM_HIST_B + (i - RR))], c);
  }
}

// ===================== exclusive prefix over 65 bins =====================
__global__ __launch_bounds__(128) void k_prefix(int* __restrict__ sm) {
  int w = threadIdx.x >> 6;
  if ((threadIdx.x & 63) == 0 && w < 2) {
    int hb = w ? SM_HIST_B : SM_HIST_A;
    int sb = w ? SM_START_B : SM_START_A;
    int cb = w ? SM_CUR_B : SM_CUR_A;
    int h[RR];
#pragma unroll
    for (int r = 0; r < RR; ++r) h[r] = sm[hb + r];
    int s = 0;
#pragma unroll
    for (int r = 0; r < RR; ++r) { sm[sb + r] = s; sm[cb + r] = s; s += h[r]; }
  }
}

// ===================== counting-sort scatter =====================
__global__ __launch_bounds__(256) void k_scatter(
    const int* __restrict__ etA, const int* __restrict__ etB,
    int* __restrict__ sm, int* __restrict__ ordA, int* __restrict__ ordB) {
  __shared__ int lhA[RR], lbA[RR], lhB[RR], lbB[RR];
  int tid = threadIdx.x;
  for (int i = tid; i < RR; i += blockDim.x) { lhA[i] = 0; lhB[i] = 0; }
  __syncthreads();
  int e = blockIdx.x * blockDim.x + tid;
  int ta = 0, tb = 0, ra = 0, rb = 0;
  bool valid = (e < NE);
  if (valid) {
    ta = etA[e]; tb = etB[e];
    ra = atomicAdd(&lhA[ta], 1);
    rb = atomicAdd(&lhB[tb], 1);
  }
  __syncthreads();
  for (int i = tid; i < RR; i += blockDim.x) {
    if (lhA[i]) lbA[i] = atomicAdd(&sm[SM_CUR_A + i], lhA[i]);
    if (lhB[i]) lbB[i] = atomicAdd(&sm[SM_CUR_B + i], lhB[i]);
  }
  __syncthreads();
  if (valid) { ordA[lbA[ta] + ra] = e; ordB[lbB[tb] + rb] = e; }
}

// ===================== counts -> 1/cnt (float, in place) =====================
__global__ __launch_bounds__(256) void k_inv(int* __restrict__ cntA, int* __restrict__ cntB) {
  int i = blockIdx.x * blockDim.x + threadIdx.x;
  if (i < NR) {
    int c = cntA[i]; ((float*)cntA)[i] = (c > 0) ? 1.0f / (float)c : 0.0f;
    c = cntB[i];     ((float*)cntB)[i] = (c > 0) ? 1.0f / (float)c : 0.0f;
  }
}

// ===================== layer-1 root term =====================
__global__ __launch_bounds__(256) void k_root1(
    const float* __restrict__ xo, const float* __restrict__ xa,
    const float* __restrict__ rt, const float* __restrict__ b,
    float* __restrict__ yo, float* __restrict__ yaa, float* __restrict__ ya) {
  int lane = threadIdx.x & 63;
  int n = (blockIdx.x * blockDim.x + threadIdx.x) >> 6;
  if (n >= NN) return;
  const float4* xo4 = (const float4*)(xo + (size_t)n * FF);
  const float4* xa4 = (const float4*)(xa + (size_t)n * FF);
  float so = b[lane], sa = so;
#pragma unroll
  for (int j = 0; j < FF / 4; ++j) {
    float vo[4], va[4];
    *(float4*)vo = xo4[j];
    *(float4*)va = xa4[j];
#pragma unroll
    for (int t = 0; t < 4; ++t) {
      float wv = rt[(4 * j + t) * H1 + lane];
      so = fmaf(vo[t], wv, so);
      sa = fmaf(va[t], wv, sa);
    }
  }
  yo[(size_t)n * H1 + lane] = so;
  yaa[(size_t)n * H1 + lane] = so;
  ya[(size_t)n * H1 + lane] = sa;
}

// ===================== layer-1 edge transform+scatter ===============================
// W_r^T staged in LDS [o=64][k=128], 16B-chunk XOR-swizzled (chunk ^= o&31) so each
// lane's ds_read_b128 of its column is bank-conflict-free.
// Edge metadata + x-row values are wave-uniform -> readfirstlane -> scalar loads,
// so per-lane state is just EPG accumulators (no spill possible).
template <int NIN, int EPG>
__global__ __launch_bounds__(256, 4) void k_edge1(
    const int* __restrict__ ei, const int* __restrict__ ord,
    const int* __restrict__ sm, int startOff, int histOff,
    const float* __restrict__ invc, const float* __restrict__ W1,
    const float* __restrict__ xA, const float* __restrict__ xB,
    float* __restrict__ yA, float* __restrict__ yB) {
  __shared__ float wlds[FF * H1];          // 32 KB
  const int r = blockIdx.x / CPB1;
  {
    const int o = threadIdx.x & 63;
    const int kb = (threadIdx.x >> 6) << 5;
    const float* Wr = W1 + (size_t)r * (FF * H1);
#pragma unroll
    for (int j = 0; j < 32; ++j) {
      const int k = kb + j;
      const int sc = (k >> 2) ^ (o & 31);
      wlds[o * 128 + sc * 4 + (k & 3)] = Wr[(size_t)k * H1 + o];
    }
  }
  __syncthreads();
  const int lane = threadIdx.x & 63;       // = output column
  const int lx = lane & 31;
  const float* wrow = wlds + lane * 128;
  const int wvid = (blockIdx.x - r * CPB1) * 4 + (threadIdx.x >> 6);
  const int stride = CPB1 * 4;
  const int s0 = __builtin_amdgcn_readfirstlane(sm[startOff + r]);
  const int cnt = __builtin_amdgcn_readfirstlane(sm[histOff + r]);
  const int ngroups = (cnt + EPG - 1) / EPG;

  for (int G = wvid; G < ngroups; G += stride) {
    const int base = s0 + G * EPG;
    const int lim = cnt - G * EPG;
    int dst[EPG];
    float inv[EPG];
    const float* pA[EPG];
    const float* pB[EPG];
#pragma unroll
    for (int i = 0; i < EPG; ++i) {
      const int pi = (i < lim) ? i : 0;
      const int e = __builtin_amdgcn_readfirstlane(ord[base + pi]);
      const int s = __builtin_amdgcn_readfirstlane(ei[e]);
      dst[i] = __builtin_amdgcn_readfirstlane(ei[NE + e]);
      const float iv = invc[(size_t)dst[i] * RR + r];
      inv[i] = (i < lim) ? iv : 0.f;
      pA[i] = xA + (size_t)s * FF;
      if constexpr (NIN == 2) pB[i] = xB + (size_t)s * FF;
    }
    float aA[EPG], aB[EPG];
#pragma unroll
    for (int i = 0; i < EPG; ++i) { aA[i] = 0.f; aB[i] = 0.f; }
#pragma unroll
    for (int c = 0; c < FF / 4; ++c) {
      const float4 w4 = *(const float4*)(wrow + ((c ^ lx) << 2));
      const int k = c << 2;
#pragma unroll
      for (int i = 0; i < EPG; ++i) {
        aA[i] = fmaf(pA[i][k],     w4.x, aA[i]);
        aA[i] = fmaf(pA[i][k + 1], w4.y, aA[i]);
        aA[i] = fmaf(pA[i][k + 2], w4.z, aA[i]);
        aA[i] = fmaf(pA[i][k + 3], w4.w, aA[i]);
        if constexpr (NIN == 2) {
          aB[i] = fmaf(pB[i][k],     w4.x, aB[i]);
          aB[i] = fmaf(pB[i][k + 1], w4.y, aB[i]);
          aB[i] = fmaf(pB[i][k + 2], w4.z, aB[i]);
          aB[i] = fmaf(pB[i][k + 3], w4.w, aB[i]);
        }
      }
    }
#pragma unroll
    for (int i = 0; i < EPG; ++i) {
      unsafeAtomicAdd(&yA[(size_t)dst[i] * H1 + lane], aA[i] * inv[i]);
      if constexpr (NIN == 2)
        unsafeAtomicAdd(&yB[(size_t)dst[i] * H1 + lane], aB[i] * inv[i]);
    }
  }
}

// ===================== relu over contiguous x1 buffers =====================
__global__ __launch_bounds__(256) void k_relu4(float4* __restrict__ a, int n4) {
  int i = blockIdx.x * blockDim.x + threadIdx.x;
  if (i < n4) {
    float4 v = a[i];
    v.x = fmaxf(v.x, 0.f); v.y = fmaxf(v.y, 0.f);
    v.z = fmaxf(v.z, 0.f); v.w = fmaxf(v.w, 0.f);
    a[i] = v;
  }
}

// ===================== layer-2 root term =====================
__global__ __launch_bounds__(256) void k_root2(
    const float* __restrict__ x1, const float* __restrict__ rt,
    const float* __restrict__ b, float* __restrict__ y) {
  int i = blockIdx.x * blockDim.x + threadIdx.x;
  if (i >= NN * H2) return;
  int o = i & (H2 - 1);
  int n = i >> 5;
  const float4* x4 = (const float4*)(x1 + (size_t)n * H1);
  float s = b[o];
#pragma unroll
  for (int j = 0; j < H1 / 4; ++j) {
    float v[4];
    *(float4*)v = x4[j];
#pragma unroll
    for (int t = 0; t < 4; ++t) s = fmaf(v[t], rt[(4 * j + t) * H2 + o], s);
  }
  y[i] = s;
}

// ===================== layer-2 edge transform+scatter ===============================
// All 64 lanes redundantly compute o = lane&31 for EPG edges (uniform x via s_load);
// wave halves split the atomic writes over edge pairs (i, i+EPG/2).
template <int NIN, int EPG>
__global__ __launch_bounds__(256, 4) void k_edge2(
    const int* __restrict__ ei, const int* __restrict__ ord,
    const int* __restrict__ sm, int startOff, int histOff,
    const float* __restrict__ invc, const float* __restrict__ W2,
    const float* __restrict__ xA, const float* __restrict__ xB,
    float* __restrict__ yA, float* __restrict__ yB) {
  __shared__ float wlds[H1 * H2];          // 8 KB, [o=32][k=64], chunk ^= o&15
  const int r = blockIdx.x / CPB2;
  {
    const int o = threadIdx.x & 31;
    const int kb = (threadIdx.x >> 5) << 3;
    const float* Wr = W2 + (size_t)r * (H1 * H2);
#pragma unroll
    for (int j = 0; j < 8; ++j) {
      const int k = kb + j;
      const int sc = (k >> 2) ^ (o & 15);
      wlds[o * 64 + sc * 4 + (k & 3)] = Wr[(size_t)k * H2 + o];
    }
  }
  __syncthreads();
  const int lane = threadIdx.x & 63;
  const int o = lane & 31;
  const int eh = lane >> 5;
  const int ox = o & 15;
  const float* wrow = wlds + o * 64;
  const int wvid = (blockIdx.x - r * CPB2) * 4 + (threadIdx.x >> 6);
  const int stride = CPB2 * 4;
  const int s0 = __builtin_amdgcn_readfirstlane(sm[startOff + r]);
  const int cnt = __builtin_amdgcn_readfirstlane(sm[histOff + r]);
  const int ngroups = (cnt + EPG - 1) / EPG;

  for (int G = wvid; G < ngroups; G += stride) {
    const int base = s0 + G * EPG;
    const int lim = cnt - G * EPG;
    int dst[EPG];
    float inv[EPG];
    const float* pA[EPG];
    const float* pB[EPG];
#pragma unroll
    for (int i = 0; i < EPG; ++i) {
      const int pi = (i < lim) ? i : 0;
      const int e = __builtin_amdgcn_readfirstlane(ord[base + pi]);
      const int s = __builtin_amdgcn_readfirstlane(ei[e]);
      dst[i] = __builtin_amdgcn_readfirstlane(ei[NE + e]);
      const float iv = invc[(size_t)dst[i] * RR + r];
      inv[i] = (i < lim) ? iv : 0.f;
      pA[i] = xA + (size_t)s * H1;
      if constexpr (NIN == 2) pB[i] = xB + (size_t)s * H1;
    }
    float aA[EPG], aB[EPG];
#pragma unroll
    for (int i = 0; i < EPG; ++i) { aA[i] = 0.f; aB[i] = 0.f; }
#pragma unroll
    for (int c = 0; c < H1 / 4; ++c) {
      const float4 w4 = *(const float4*)(wrow + ((c ^ ox) << 2));
      const int k = c << 2;
#pragma unroll
      for (int i = 0; i < EPG; ++i) {
        aA[i] = fmaf(pA[i][k],     w4.x, aA[i]);
        aA[i] = fmaf(pA[i][k + 1], w4.y, aA[i]);
        aA[i] = fmaf(pA[i][k + 2], w4.z, aA[i]);
        aA[i] = fmaf(pA[i][k + 3], w4.w, aA[i]);
        if constexpr (NIN == 2) {
          aB[i] = fmaf(pB[i][k],     w4.x, aB[i]);
          aB[i] = fmaf(pB[i][k + 1], w4.y, aB[i]);
          aB[i] = fmaf(pB[i][k + 2], w4.z, aB[i]);
          aB[i] = fmaf(pB[i][k + 3], w4.w, aB[i]);
        }
      }
    }
#pragma unroll
    for (int i = 0; i < EPG / 2; ++i) {
      const int j = i + EPG / 2;
      const int dsel = eh ? dst[j] : dst[i];
      const float vA = eh ? aA[j] * inv[j] : aA[i] * inv[i];
      unsafeAtomicAdd(&yA[(size_t)dsel * H2 + o], vA);
      if constexpr (NIN == 2) {
        const float vB = eh ? aB[j] * inv[j] : aB[i] * inv[i];
        unsafeAtomicAdd(&yB[(size_t)dsel * H2 + o], vB);
      }
    }
  }
}

// ===================== column sum of x2_o -> hacc[32] =====================
__global__ __launch_bounds__(256) void k_colsum(const float* __restrict__ x2o,
                                                float* __restrict__ hacc) {
  int tid = threadIdx.x;
  int col = tid & 31;
  int rgrp = blockIdx.x * (blockDim.x >> 5) + (tid >> 5);
  int nth = gridDim.x * (blockDim.x >> 5);
  float s = 0.f;
  for (int n = rgrp; n < NN; n += nth) s += x2o[(size_t)n * H2 + col];
  unsafeAtomicAdd(&hacc[col], s);
}

// ===================== h_os = sigmoid(mean); v = disc_w @ h_os =====================
__global__ __launch_bounds__(64) void k_disc(const float* __restrict__ hacc,
                                             const float* __restrict__ dw,
                                             float* __restrict__ vout) {
  __shared__ float hos[H2];
  int t = threadIdx.x;
  if (t < H2) hos[t] = 1.0f / (1.0f + expf(-hacc[t] / (float)NN));
  __syncthreads();
  if (t < H2) {
    float s = 0.f;
#pragma unroll
    for (int k = 0; k < H2; ++k) s = fmaf(dw[t * H2 + k], hos[k], s);
    vout[t] = s;
  }
}

// ===================== ret_os / ret_os_a (col0 shared) =====================
__global__ __launch_bounds__(256) void k_ret(
    const float* __restrict__ x2o, const float* __restrict__ x2oa, const float* __restrict__ x2oaa,
    const float* __restrict__ v, const float* __restrict__ db,
    float* __restrict__ ros, float* __restrict__ rosa) {
  int n = blockIdx.x * blockDim.x + threadIdx.x;
  if (n >= NN) return;
  const float4* a4 = (const float4*)(x2o + (size_t)n * H2);
  const float4* b4 = (const float4*)(x2oa + (size_t)n * H2);
  const float4* c4 = (const float4*)(x2oaa + (size_t)n * H2);
  const float4* v4 = (const float4*)v;
  float r0 = 0.f, r1 = 0.f, r2 = 0.f;
#pragma unroll
  for (int j = 0; j < H2 / 4; ++j) {
    float va[4], vb[4], vc[4], vv[4];
    *(float4*)va = a4[j]; *(float4*)vb = b4[j]; *(float4*)vc = c4[j]; *(float4*)vv = v4[j];
#pragma unroll
    for (int t = 0; t < 4; ++t) {
      r0 = fmaf(va[t], vv[t], r0);
      r1 = fmaf(vb[t], vv[t], r1);
      r2 = fmaf(vc[t], vv[t], r2);
    }
  }
  float bb = db[0];
  ros[n * 2] = r0 + bb;  ros[n * 2 + 1] = r1 + bb;
  rosa[n * 2] = r0 + bb; rosa[n * 2 + 1] = r2 + bb;
}

// ===================== classifier: log[b][r] =====================
__global__ __launch_bounds__(128) void k_cls(
    const int* __restrict__ idx, const float* __restrict__ x1o, const float* __restrict__ x2o,
    const float* __restrict__ attt, const float* __restrict__ cw, const float* __restrict__ cb,
    float* __restrict__ lg) {
  int b = blockIdx.x;
  int r = threadIdx.x;
  if (r >= RR) return;
  int i1 = idx[b], i2 = idx[BQ + b];
  float a0 = attt[0], a1 = attt[1];
  float acc = cb[r];
  const float4* q1 = (const float4*)(x1o + (size_t)i1 * H1);
  const float4* q2 = (const float4*)(x2o + (size_t)i1 * H2);
  const float4* q3 = (const float4*)(x1o + (size_t)i2 * H1);
  const float4* q4 = (const float4*)(x2o + (size_t)i2 * H2);
#pragma unroll
  for (int j = 0; j < H1 / 4; ++j) {
    float v[4]; *(float4*)v = q1[j];
#pragma unroll
    for (int t = 0; t < 4; ++t) acc = fmaf(a0 * v[t], cw[(4 * j + t) * RR + r], acc);
  }
#pragma unroll
  for (int j = 0; j < H2 / 4; ++j) {
    float v[4]; *(float4*)v = q2[j];
#pragma unroll
    for (int t = 0; t < 4; ++t) acc = fmaf(a1 * v[t], cw[(H1 + 4 * j + t) * RR + r], acc);
  }
#pragma unroll
  for (int j = 0; j < H1 / 4; ++j) {
    float v[4]; *(float4*)v = q3[j];
#pragma unroll
    for (int t = 0; t < 4; ++t) acc = fmaf(a0 * v[t], cw[(96 + 4 * j + t) * RR + r], acc);
  }
#pragma unroll
  for (int j = 0; j < H2 / 4; ++j) {
    float v[4]; *(float4*)v = q4[j];
#pragma unroll
    for (int t = 0; t < 4; ++t) acc = fmaf(a1 * v[t], cw[(96 + H1 + 4 * j + t) * RR + r], acc);
  }
  lg[(size_t)b * RR + r] = acc;
}

// ===================== launch =====================
extern "C" void kernel_launch(void* const* d_in, const int* in_sizes, int n_in,
                              void* d_out, int out_size, void* d_ws, size_t ws_size,
                              hipStream_t stream) {
  const float* x_o  = (const float*)d_in[0];
  const float* x_a  = (const float*)d_in[1];
  const int*   ei   = (const int*)d_in[2];
  const int*   etA  = (const int*)d_in[3];
  const int*   etB  = (const int*)d_in[4];
  const int*   idx  = (const int*)d_in[5];
  const float* W1   = (const float*)d_in[6];
  const float* rt1  = (const float*)d_in[7];
  const float* b1   = (const float*)d_in[8];
  const float* W2   = (const float*)d_in[9];
  const float* rt2  = (const float*)d_in[10];
  const float* b2   = (const float*)d_in[11];
  const float* attt = (const float*)d_in[12];
  const float* dw   = (const float*)d_in[13];
  const float* db   = (const float*)d_in[14];
  const float* cw   = (const float*)d_in[15];
  const float* cb   = (const float*)d_in[16];

  const size_t NRp = 1300224;
  int* wsI  = (int*)d_ws;
  int* cntA = wsI;
  int* cntB = wsI + NRp;
  int* sm   = wsI + 2 * NRp;
  int* ordA = sm + 1024;
  int* ordB = ordA + NE;
  float* x1o   = (float*)(ordB + NE);
  float* x1a   = x1o + (size_t)NN * H1;
  float* x1aa  = x1a + (size_t)NN * H1;
  float* x2oa  = x1aa + (size_t)NN * H1;
  float* x2oaa = x2oa + (size_t)NN * H2;
  float* smF   = (float*)sm;
  float* hacc  = smF + SM_HACC;
  float* vbuf  = smF + SM_V;

  float* outF   = (float*)d_out;
  float* o_log  = outF;
  float* o_ros  = outF + (size_t)BQ * RR;
  float* o_rosa = o_ros + (size_t)NN * 2;
  float* o_x2o  = o_rosa + (size_t)NN * 2;

  hipMemsetAsync(wsI, 0, (2 * NRp + 1024) * sizeof(int), stream);

  k_hist<<<(NE + 255) / 256, 256, 0, stream>>>(ei, etA, etB, cntA, cntB, sm);
  k_prefix<<<1, 128, 0, stream>>>(sm);
  k_scatter<<<(NE + 255) / 256, 256, 0, stream>>>(etA, etB, sm, ordA, ordB);
  k_inv<<<(NR + 255) / 256, 256, 0, stream>>>(cntA, cntB);

  k_root1<<<(NN * H1) / 256, 256, 0, stream>>>(x_o, x_a, rt1, b1, x1o, x1aa, x1a);
  k_edge1<2, 4><<<RR * CPB1, 256, 0, stream>>>(ei, ordA, sm, SM_START_A, SM_HIST_A,
                                               (const float*)cntA, W1, x_o, x_a, x1o, x1a);
  k_edge1<1, 8><<<RR * CPB1, 256, 0, stream>>>(ei, ordB, sm, SM_START_B, SM_HIST_B,
                                               (const float*)cntB, W1, x_o, nullptr, x1aa, nullptr);
  k_relu4<<<(3 * NN * H1 / 4 + 255) / 256, 256, 0, stream>>>((float4*)x1o, 3 * NN * H1 / 4);

  k_root2<<<(NN * H2 + 255) / 256, 256, 0, stream>>>(x1o, rt2, b2, o_x2o);
  k_root2<<<(NN * H2 + 255) / 256, 256, 0, stream>>>(x1a, rt2, b2, x2oa);
  k_root2<<<(NN * H2 + 255) / 256, 256, 0, stream>>>(x1aa, rt2, b2, x2oaa);
  k_edge2<2, 8><<<RR * CPB2, 256, 0, stream>>>(ei, ordA, sm, SM_START_A, SM_HIST_A,
                                               (const float*)cntA, W2, x1o, x1a, o_x2o, x2oa);
  k_edge2<1, 8><<<RR * CPB2, 256, 0, stream>>>(ei, ordB, sm, SM_START_B, SM_HIST_B,
                                               (const float*)cntB, W2, x1aa, nullptr, x2oaa, nullptr);

  k_colsum<<<128, 256, 0, stream>>>(o_x2o, hacc);
  k_disc<<<1, 64, 0, stream>>>(hacc, dw, vbuf);
  k_ret<<<(NN + 255) / 256, 256, 0, stream>>>(o_x2o, x2oa, x2oaa, vbuf, db, o_ros, o_rosa);
  k_cls<<<BQ, 128, 0, stream>>>(idx, x1o, o_x2o, attt, cw, cb, o_log);
}